// Round 7
// baseline (563.613 us; speedup 1.0000x reference)
//
#include <hip/hip_runtime.h>
#include <hip/hip_cooperative_groups.h>
#include <stdint.h>

namespace cg = cooperative_groups;

// Problem constants (SparseMPNN_30709016166923): B=2, N=40000, E=640000, H=4, F=32
#define BB     2
#define NNODE  40000
#define NEDGE  640000
#define NH     4
#define NF     32
#define NHF    128   // NH*NF
#define SEGN   (BB * NNODE)          // 80000 segments (b,node)
#define GEDGE  (BB * NEDGE)          // 1,280,000 global edges
#define SLOT   48                    // per-node bucket capacity (deg~Poisson(16))

// two-phase binning
#define W      512                   // nodes per coarse bucket (pow2)
#define NBK_B  79                    // ceil(40000/512) buckets per batch
#define NBK    (BB * NBK_B)          // 158 coarse buckets
#define CAP    9216                  // pairs per coarse bucket (mean 8192, +11 sigma)
#define BLK_E  2048                  // edges per binA chunk
#define NCHUNK (GEDGE / BLK_E)       // 625 (exact)
#define MAXG   1536                  // 6 blocks/CU x 256 CUs (LDS 25.6KB -> 6/CU)

static constexpr float NEG_SLOPE = 0.2f;
static constexpr float NEG_BIG   = -3.4e38f;

// ============================================================================
// R15: single cooperative mega-kernel. Rationale: R6 accounting shows
// ~95us of the 128us non-gather time is unexplained by work arithmetic
// (prep 7 + binA 20 + binB 6 ~= 33us of real work) -> suspected inter-dispatch
// drain/ramp overhead. One dispatch + 3 grid.sync()s eliminates it if so.
// Phase LDS shared via union: binA 12.2KB / binB(half-bucket) 25.6KB ->
// 6 blocks/CU, grid 1536 co-resident, 24 waves/CU (same as standalone gather).
// ============================================================================
union SharedU {
    struct {
        unsigned hist[NBK], lofs[NBK], gofs[NBK], wsum[4];
        unsigned staged[BLK_E];
        unsigned char sbk[BLK_E];
    } a;                                        // 12,152 B
    struct {
        unsigned short loc[256 * SLOT];         // 24,576 B
        unsigned dloc[256];
    } b;                                        // 25,600 B
};

__global__ __launch_bounds__(256, 6) void mega_k(
        const int* __restrict__ tg, const int* __restrict__ sc,
        const float* __restrict__ X,
        const float* __restrict__ As, const float* __restrict__ Aa,
        float* __restrict__ S, float* __restrict__ A,
        unsigned* __restrict__ cursor, unsigned* __restrict__ pairs,
        unsigned short* __restrict__ srt, unsigned* __restrict__ deg,
        float* __restrict__ OUT) {
    __shared__ SharedU shm;
    cg::grid_group grid = cg::this_grid();
    int t = threadIdx.x;
    int gtid = blockIdx.x * 256 + t;
    int gsz = gridDim.x * 256;

    // ---------------- phase 0: per-(b,n,h) logits + cursor zero ----------------
    for (int idx = gtid; idx < SEGN * NH; idx += gsz) {
        int h = idx & (NH - 1);
        const float4* xv = (const float4*)(X + (size_t)idx * NF);
        const float4* sv = (const float4*)(As + h * NF);
        const float4* av = (const float4*)(Aa + h * NF);
        float s = 0.f, a = 0.f;
#pragma unroll
        for (int i = 0; i < 8; ++i) {
            float4 x = xv[i];
            float4 ws = sv[i];
            float4 wa = av[i];
            s += x.x * ws.x + x.y * ws.y + x.z * ws.z + x.w * ws.w;
            a += x.x * wa.x + x.y * wa.y + x.z * wa.z + x.w * wa.w;
        }
        S[idx] = s;
        A[idx] = a;
    }
    for (int i = gtid; i < NBK; i += gsz) cursor[i] = 0u;
    grid.sync();

    // ---------------- phase 1: binA (coarse partition, LDS-sorted writes) -----
    for (int chunk = blockIdx.x; chunk < NCHUNK; chunk += gridDim.x) {
        int base = chunk * BLK_E;
        for (int i = t; i < NBK; i += 256) shm.a.hist[i] = 0u;
        __syncthreads();

        unsigned pr[8];
        unsigned short pbk[8], plp[8];
#pragma unroll
        for (int k = 0; k < 8; ++k) {
            int e = base + k * 256 + t;                // exact: 625*2048 == GEDGE
            int tgv = __builtin_nontemporal_load(tg + e);
            int scv = __builtin_nontemporal_load(sc + e);
            int b = (e >= NEDGE) ? 1 : 0;
            unsigned bk = (unsigned)(b * NBK_B + (tgv >> 9));
            pr[k]  = ((unsigned)(tgv & (W - 1)) << 16) | (unsigned)scv;
            pbk[k] = (unsigned short)bk;
            plp[k] = (unsigned short)atomicAdd(&shm.a.hist[bk], 1u);
        }
        __syncthreads();
        {   // parallel exclusive scan of hist[0..NBK) -> lofs
            int lane = t & 63, w = t >> 6;
            unsigned v = (t < NBK) ? shm.a.hist[t] : 0u;
            unsigned inc = v;
#pragma unroll
            for (int d = 1; d < 64; d <<= 1) {
                unsigned u = __shfl_up(inc, d);
                if (lane >= d) inc += u;
            }
            if (lane == 63) shm.a.wsum[w] = inc;
            __syncthreads();
            unsigned woff = 0;
#pragma unroll
            for (int i = 0; i < 3; ++i) { if (i < w) woff += shm.a.wsum[i]; }
            if (t < NBK) {
                shm.a.lofs[t] = woff + inc - v;        // exclusive prefix
                if (v > 0u)
                    shm.a.gofs[t] = atomicAdd(&cursor[t], v);
            }
        }
        __syncthreads();
#pragma unroll
        for (int k = 0; k < 8; ++k) {
            unsigned j = shm.a.lofs[pbk[k]] + plp[k];
            shm.a.staged[j] = pr[k];
            shm.a.sbk[j] = (unsigned char)pbk[k];
        }
        __syncthreads();
        for (int j = t; j < BLK_E; j += 256) {
            unsigned bk = shm.a.sbk[j];
            unsigned dst = shm.a.gofs[bk] + ((unsigned)j - shm.a.lofs[bk]);
            if (dst < CAP)                              // 11-sigma guard
                __builtin_nontemporal_store(shm.a.staged[j],
                                            pairs + (size_t)bk * CAP + dst);
        }
        __syncthreads();                                // staged stable before next reset
    }
    grid.sync();

    // ---------------- phase 2: binB (fine-bin, half-bucket = 256 nodes) -------
    for (int task = blockIdx.x; task < NBK * 2; task += gridDim.x) {
        int gbk = task >> 1, half = task & 1;
        int b = gbk / NBK_B;
        int bkloc = gbk - b * NBK_B;
        int nstart = bkloc * W + half * 256;            // node offset within batch
        int wEff = min(256, NNODE - nstart);            // <=0 for tail phantom halves
        shm.b.dloc[t] = 0u;
        __syncthreads();
        int nE = (wEff > 0) ? (int)min(cursor[gbk], (unsigned)CAP) : 0;
        const unsigned* pb = pairs + (size_t)gbk * CAP;
        for (int j = t; j < nE; j += 256) {
            unsigned p = __builtin_nontemporal_load(pb + j);
            int tl = (int)(p >> 16) - half * 256;       // node local to half-bucket
            if (0 <= tl && tl < 256) {
                unsigned pos = atomicAdd(&shm.b.dloc[tl], 1u);
                if (pos < SLOT)
                    shm.b.loc[tl * SLOT + pos] = (unsigned short)(p & 0xFFFFu);
            }
        }
        __syncthreads();
        if (wEff > 0) {
            int node0 = b * NNODE + nstart;
            unsigned* srt32 = (unsigned*)(srt + (size_t)node0 * SLOT); // 96B/node
            const unsigned* loc32 = (const unsigned*)shm.b.loc;
            int n32 = wEff * SLOT / 2;
            for (int i = t; i < n32; i += 256)
                __builtin_nontemporal_store(loc32[i], srt32 + i);
            for (int i = t; i < wEff; i += 256)
                __builtin_nontemporal_store(shm.b.dloc[i], deg + node0 + i);
        }
        __syncthreads();                                // loc/dloc stable before reset
    }
    grid.sync();

    // ---------------- phase 3: gather (R3 guarded form — best measured) -------
    {
        int lane = t & 63;
        int wv = t >> 6;
        int hs = lane & 3;                      // staging head
        int es = lane >> 2;                     // staging edge slot 0..15 per group
        int h32 = lane >> 5;                    // which edge of the pair
        int q = lane & 31;                      // f-quad index 0..31
        int haq = q >> 3;                       // accumulation head for quad
        for (int node = blockIdx.x * 4 + wv; node < SEGN; node += gridDim.x * 4) {
            int dg = min((int)deg[node], SLOT);
            int bbase = (node >= NNODE) ? NNODE : 0;
            size_t beg = (size_t)node * SLOT;
            float sH = S[node * NH + hs];

            float v[3];
            int   sb[3];
#pragma unroll
            for (int c = 0; c < 3; ++c) {
                int e = 16 * c + es;
                int s0 = bbase;
                float vv = NEG_BIG;
                if (e < dg) {
                    s0 = bbase + (int)srt[beg + e];
                    vv = sH + A[s0 * NH + hs];
                    vv = vv > 0.f ? vv : NEG_SLOPE * vv;
                }
                sb[c] = s0;
                v[c]  = vv;
            }
            float m = fmaxf(fmaxf(v[0], v[1]), v[2]);
            m = fmaxf(m, __shfl_xor(m, 4));
            m = fmaxf(m, __shfl_xor(m, 8));
            m = fmaxf(m, __shfl_xor(m, 16));
            m = fmaxf(m, __shfl_xor(m, 32));
            float w[3];
#pragma unroll
            for (int c = 0; c < 3; ++c)
                w[c] = (16 * c + es < dg) ? __expf(v[c] - m) : 0.f;

            float4 acc = make_float4(0.f, 0.f, 0.f, 0.f);
#pragma unroll
            for (int i = 0; i < 24; ++i) {
                if (2 * i < dg) {               // wave-uniform guard
                    int e2 = 2 * i + h32;
                    float we  = __shfl(w[i >> 3],  4 * (e2 & 15) + haq);
                    int   sbe = __shfl(sb[i >> 3], 4 * (e2 & 15));
                    const float4 x = *(const float4*)(X + (size_t)sbe * NHF + 4 * q);
                    acc.x += x.x * we;
                    acc.y += x.y * we;
                    acc.z += x.z * we;
                    acc.w += x.w * we;
                }
            }
            acc.x += __shfl_xor(acc.x, 32);
            acc.y += __shfl_xor(acc.y, 32);
            acc.z += __shfl_xor(acc.z, 32);
            acc.w += __shfl_xor(acc.w, 32);
            if (lane < 32) {
                float4* o = (float4*)(OUT + (size_t)node * NHF + 4 * q);
                *o = acc;                       // every node written: no OUT init
            }
        }
    }
}

// ---------------- fallback path (proven R3 kernels), used only if the --------
// ---------------- cooperative launch is refused by the runtime ---------------
__global__ void prep_k(const float* __restrict__ X, const float* __restrict__ As,
                       const float* __restrict__ Aa, float* __restrict__ S,
                       float* __restrict__ A, unsigned* __restrict__ cursor) {
    int idx = blockIdx.x * blockDim.x + threadIdx.x;
    if (idx < NBK) cursor[idx] = 0u;
    if (idx >= SEGN * NH) return;
    int h = idx & (NH - 1);
    const float4* xv = (const float4*)(X + (size_t)idx * NF);
    const float4* sv = (const float4*)(As + h * NF);
    const float4* av = (const float4*)(Aa + h * NF);
    float s = 0.f, a = 0.f;
#pragma unroll
    for (int i = 0; i < 8; ++i) {
        float4 x = xv[i], ws = sv[i], wa = av[i];
        s += x.x * ws.x + x.y * ws.y + x.z * ws.z + x.w * ws.w;
        a += x.x * wa.x + x.y * wa.y + x.z * wa.z + x.w * wa.w;
    }
    S[idx] = s;
    A[idx] = a;
}

__global__ __launch_bounds__(256) void binA_k(const int* __restrict__ tg,
                                              const int* __restrict__ sc,
                                              unsigned* __restrict__ cursor,
                                              unsigned* __restrict__ pairs) {
    __shared__ unsigned hist[NBK], lofs[NBK], gofs[NBK], wsum[4];
    __shared__ unsigned staged[BLK_E];
    __shared__ unsigned char sbk[BLK_E];
    int t = threadIdx.x;
    int base = blockIdx.x * BLK_E;
    for (int i = t; i < NBK; i += 256) hist[i] = 0u;
    __syncthreads();
    unsigned pr[8];
    unsigned short pbk[8], plp[8];
#pragma unroll
    for (int k = 0; k < 8; ++k) {
        int e = base + k * 256 + t;
        int tgv = tg[e], scv = sc[e];
        int b = (e >= NEDGE) ? 1 : 0;
        unsigned bk = (unsigned)(b * NBK_B + (tgv >> 9));
        pr[k]  = ((unsigned)(tgv & (W - 1)) << 16) | (unsigned)scv;
        pbk[k] = (unsigned short)bk;
        plp[k] = (unsigned short)atomicAdd(&hist[bk], 1u);
    }
    __syncthreads();
    {
        int lane = t & 63, w = t >> 6;
        unsigned v = (t < NBK) ? hist[t] : 0u;
        unsigned inc = v;
#pragma unroll
        for (int d = 1; d < 64; d <<= 1) {
            unsigned u = __shfl_up(inc, d);
            if (lane >= d) inc += u;
        }
        if (lane == 63) wsum[w] = inc;
        __syncthreads();
        unsigned woff = 0;
#pragma unroll
        for (int i = 0; i < 3; ++i) { if (i < w) woff += wsum[i]; }
        if (t < NBK) {
            lofs[t] = woff + inc - v;
            if (v > 0u) gofs[t] = atomicAdd(&cursor[t], v);
        }
    }
    __syncthreads();
#pragma unroll
    for (int k = 0; k < 8; ++k) {
        unsigned j = lofs[pbk[k]] + plp[k];
        staged[j] = pr[k];
        sbk[j] = (unsigned char)pbk[k];
    }
    __syncthreads();
    for (int j = t; j < BLK_E; j += 256) {
        unsigned bk = sbk[j];
        unsigned dst = gofs[bk] + ((unsigned)j - lofs[bk]);
        if (dst < CAP) pairs[(size_t)bk * CAP + dst] = staged[j];
    }
}

__global__ __launch_bounds__(1024) void binB_k(const unsigned* __restrict__ cursor,
                                               const unsigned* __restrict__ pairs,
                                               unsigned short* __restrict__ srt,
                                               unsigned* __restrict__ deg) {
    __shared__ unsigned short loc[W * SLOT];
    __shared__ unsigned dloc[W];
    int t = threadIdx.x;
    int gbk = blockIdx.x;
    int b = gbk / NBK_B;
    int bkloc = gbk - b * NBK_B;
    int node0 = b * NNODE + bkloc * W;
    int wEff = min(W, NNODE - bkloc * W);
    for (int i = t; i < W; i += 1024) dloc[i] = 0u;
    __syncthreads();
    int nE = (int)min(cursor[gbk], (unsigned)CAP);
    const unsigned* pb = pairs + (size_t)gbk * CAP;
    for (int j = t; j < nE; j += 1024) {
        unsigned p = pb[j];
        unsigned tl = p >> 16;
        unsigned pos = atomicAdd(&dloc[tl], 1u);
        if (pos < SLOT) loc[tl * SLOT + pos] = (unsigned short)(p & 0xFFFFu);
    }
    __syncthreads();
    unsigned* srt32 = (unsigned*)(srt + (size_t)node0 * SLOT);
    const unsigned* loc32 = (const unsigned*)loc;
    int n32 = wEff * SLOT / 2;
    for (int i = t; i < n32; i += 1024) srt32[i] = loc32[i];
    for (int i = t; i < wEff; i += 1024) deg[node0 + i] = dloc[i];
}

__global__ __launch_bounds__(256) void gather_k(
        const float* __restrict__ X, const float* __restrict__ S,
        const float* __restrict__ A, const unsigned* __restrict__ deg,
        const unsigned short* __restrict__ srt, float* __restrict__ OUT) {
    int node = blockIdx.x * 4 + (threadIdx.x >> 6);
    int t = threadIdx.x & 63;
    int hs = t & 3, es = t >> 2, h32 = t >> 5, q = t & 31, haq = q >> 3;
    int dg = min((int)deg[node], SLOT);
    int bbase = (node >= NNODE) ? NNODE : 0;
    size_t beg = (size_t)node * SLOT;
    float sH = S[node * NH + hs];
    float v[3]; int sb[3];
#pragma unroll
    for (int c = 0; c < 3; ++c) {
        int e = 16 * c + es;
        int s0 = bbase;
        float vv = NEG_BIG;
        if (e < dg) {
            s0 = bbase + (int)srt[beg + e];
            vv = sH + A[s0 * NH + hs];
            vv = vv > 0.f ? vv : NEG_SLOPE * vv;
        }
        sb[c] = s0; v[c] = vv;
    }
    float m = fmaxf(fmaxf(v[0], v[1]), v[2]);
    m = fmaxf(m, __shfl_xor(m, 4));
    m = fmaxf(m, __shfl_xor(m, 8));
    m = fmaxf(m, __shfl_xor(m, 16));
    m = fmaxf(m, __shfl_xor(m, 32));
    float w[3];
#pragma unroll
    for (int c = 0; c < 3; ++c)
        w[c] = (16 * c + es < dg) ? __expf(v[c] - m) : 0.f;
    float4 acc = make_float4(0.f, 0.f, 0.f, 0.f);
#pragma unroll
    for (int i = 0; i < 24; ++i) {
        if (2 * i < dg) {
            int e2 = 2 * i + h32;
            float we  = __shfl(w[i >> 3],  4 * (e2 & 15) + haq);
            int   sbe = __shfl(sb[i >> 3], 4 * (e2 & 15));
            const float4 x = *(const float4*)(X + (size_t)sbe * NHF + 4 * q);
            acc.x += x.x * we; acc.y += x.y * we;
            acc.z += x.z * we; acc.w += x.w * we;
        }
    }
    acc.x += __shfl_xor(acc.x, 32);
    acc.y += __shfl_xor(acc.y, 32);
    acc.z += __shfl_xor(acc.z, 32);
    acc.w += __shfl_xor(acc.w, 32);
    if (t < 32) *(float4*)(OUT + (size_t)node * NHF + 4 * q) = acc;
}

extern "C" void kernel_launch(void* const* d_in, const int* in_sizes, int n_in,
                              void* d_out, int out_size, void* d_ws, size_t ws_size,
                              hipStream_t stream) {
    const float* X  = (const float*)d_in[0];
    const float* As = (const float*)d_in[1];
    const float* Aa = (const float*)d_in[2];
    const int* tg = (const int*)d_in[4];
    const int* sc = (const int*)d_in[5];
    float* OUT = (float*)d_out;

    // Workspace layout, total 16,385,152 B (proven safe: R7 ran with ws_size
    // >= 18,240,000; R1 proved ~24.3MB overflows and corrupts harness state):
    //   S      @ 0          : 1,280,000  (SEGN*NH fp32)
    //   A      @ 1,280,000  : 1,280,000
    //   deg    @ 2,560,000  :   320,000  (SEGN u32)
    //   cursor @ 2,880,000  :       640  (NBK u32, padded)
    //   pairs  @ 2,880,640  : 5,824,512  (NBK*CAP u32)
    //   srt    @ 8,705,152  : 7,680,000  (SEGN*SLOT u16)
    char* ws = (char*)d_ws;
    float*          S      = (float*)ws;
    float*          A      = (float*)(ws + 1280000);
    unsigned*       deg    = (unsigned*)(ws + 2560000);
    unsigned*       cursor = (unsigned*)(ws + 2880000);
    unsigned*       pairs  = (unsigned*)(ws + 2880640);
    unsigned short* srt    = (unsigned short*)(ws + 8705152);

    static int G = 0;                    // co-resident grid, computed once
    if (G == 0) {
        int nb = 0;
        hipError_t oc = hipOccupancyMaxActiveBlocksPerMultiprocessor(&nb, mega_k, 256, 0);
        int cus = 0;
        hipDeviceGetAttribute(&cus, hipDeviceAttributeMultiprocessorCount, 0);
        if (oc != hipSuccess || nb <= 0 || cus <= 0) G = -1;   // fall back
        else {
            G = nb * cus;
            if (G > MAXG) G = MAXG;
        }
    }

    bool launched = false;
    if (G > 0) {
        void* args[] = {(void*)&tg, (void*)&sc, (void*)&X, (void*)&As, (void*)&Aa,
                        (void*)&S, (void*)&A, (void*)&cursor, (void*)&pairs,
                        (void*)&srt, (void*)&deg, (void*)&OUT};
        hipError_t rc = hipLaunchCooperativeKernel((void*)mega_k, dim3(G), dim3(256),
                                                   args, 0, stream);
        if (rc == hipSuccess) launched = true;
        else G = -1;                     // don't retry next iterations
    }
    if (!launched) {                     // proven R3 4-kernel fallback
        const int nlog = SEGN * NH;
        prep_k<<<(nlog + 255) / 256, 256, 0, stream>>>(X, As, Aa, S, A, cursor);
        binA_k<<<NCHUNK, 256, 0, stream>>>(tg, sc, cursor, pairs);
        binB_k<<<NBK, 1024, 0, stream>>>(cursor, pairs, srt, deg);
        gather_k<<<SEGN / 4, 256, 0, stream>>>(X, S, A, deg, srt, OUT);
    }
}

// Round 8
// 305.564 us; speedup vs baseline: 1.8445x; 1.8445x over previous
//
#include <hip/hip_runtime.h>
#include <stdint.h>

// Problem constants (SparseMPNN_30709016166923): B=2, N=40000, E=640000, H=4, F=32
#define BB     2
#define NNODE  40000
#define NEDGE  640000
#define NH     4
#define NF     32
#define NHF    128   // NH*NF
#define SEGN   (BB * NNODE)          // 80000 segments (b,node)
#define GEDGE  (BB * NEDGE)          // 1,280,000 global edges
#define SLOT   48                    // per-node slot capacity (deg~Poisson(16), P(>48)~1e-11)

// R16: fine-grained direct binning (64-node buckets), binB fused into gather.
#define FW     64                    // nodes per fine bucket
#define NFB_B  625                   // NNODE/FW exact
#define NFB    (BB * NFB_B)          // 1250 buckets
#define NREP   4                     // cursor replication (spread atomic hot lines)
#define RCAP   384                   // per-replica region: mean 256, sigma 16 -> +8 sigma
#define CAPF   (NREP * RCAP)         // 1536 pair slots per bucket (mean 1024)
#define BLK_E  2048                  // edges per binD block
#define NBLKD  (GEDGE / BLK_E)       // 625 exact

static constexpr float NEG_SLOPE = 0.2f;
static constexpr float NEG_BIG   = -3.4e38f;

// ---------- kernel 1: per-(b,n,h) attention logits ----------
__global__ __launch_bounds__(256) void prep_k(const float* __restrict__ X,
                                              const float* __restrict__ As,
                                              const float* __restrict__ Aa,
                                              float* __restrict__ S,
                                              float* __restrict__ A) {
    int idx = blockIdx.x * blockDim.x + threadIdx.x;   // exact: 1250*256 == 320000
    int h = idx & (NH - 1);
    const float4* xv = (const float4*)(X + (size_t)idx * NF);
    const float4* sv = (const float4*)(As + h * NF);
    const float4* av = (const float4*)(Aa + h * NF);
    float s = 0.f, a = 0.f;
#pragma unroll
    for (int i = 0; i < 8; ++i) {
        float4 x = xv[i];
        float4 ws = sv[i];
        float4 wa = av[i];
        s += x.x * ws.x + x.y * ws.y + x.z * ws.z + x.w * ws.w;
        a += x.x * wa.x + x.y * wa.y + x.z * wa.z + x.w * wa.w;
    }
    S[idx] = s;
    A[idx] = a;
}

// ---------- kernel 2: direct fine binning ----------
// One global atomicAdd per edge on a x4-replicated cursor (replica = blockIdx&3):
// R2's atomic disaster was 4 CONSECUTIVE same-line atomics per edge; this is 1
// atomic to lines spread over 20KB, ~320 ops per 4B counter, pipelined at L2.
// Pair payload: (node&63)<<16 | src. Scattered u32 stores land in the 7.68MB
// pairs region -> fully L2-absorbed (RMW merging at byte granularity; no reader
// until next dispatch, so cross-XCD non-coherence is irrelevant).
__global__ __launch_bounds__(256) void binD_k(const int* __restrict__ tg,
                                              const int* __restrict__ sc,
                                              unsigned* __restrict__ cursor4,
                                              unsigned* __restrict__ pairs) {
    int t = threadIdx.x;
    int base = blockIdx.x * BLK_E;
    int rep = blockIdx.x & (NREP - 1);
#pragma unroll
    for (int k = 0; k < 8; ++k) {
        int e = base + k * 256 + t;                    // exact: 625*2048 == GEDGE
        int tgv = __builtin_nontemporal_load(tg + e);
        int scv = __builtin_nontemporal_load(sc + e);
        int b = (e >= NEDGE) ? 1 : 0;
        int fb = b * NFB_B + (tgv >> 6);               // fine bucket (64 nodes)
        unsigned pos = atomicAdd(&cursor4[fb * NREP + rep], 1u);
        if (pos < RCAP)                                // +8-sigma guard per replica
            __builtin_nontemporal_store(
                ((unsigned)(tgv & (FW - 1)) << 16) | (unsigned)scv,
                pairs + (size_t)fb * CAPF + rep * RCAP + pos);
    }
}

// ---------- kernel 3: fused fine-bin + gather ----------
// One block per 64-node bucket (1250 blocks, balanced: 1024±32 edges each).
// Phase A: read the bucket's 4 replica regions (contiguous, L2/LLC-warm from
// binD), bin into per-node LDS slot lists (6.4KB). Phase B: 4 waves x 16 nodes
// run the PROVEN R3 gather body verbatim, with srt/deg reads replaced by LDS
// (ds_read vs ~400ns global -> shorter dependent chain). Eliminates srt+deg
// global round-trip (~16MB) and the binB dispatch entirely; the binning cost
// hides under gather's fetch-bound phase.
// m2 = segment_max(exp(v-m1)) == 1.0 exactly and 1.0f+1e-9f == 1.0f -> no
// second normalization pass (verified R3-R7, absmax 0.03125).
__global__ __launch_bounds__(256) void gat_k(const float* __restrict__ X,
                                             const float* __restrict__ S,
                                             const float* __restrict__ A,
                                             const unsigned* __restrict__ cursor4,
                                             const unsigned* __restrict__ pairs,
                                             float* __restrict__ OUT) {
    __shared__ unsigned short loc[FW * SLOT];          // 6,144 B
    __shared__ unsigned dloc[FW];                      //   256 B
    int t = threadIdx.x;
    int fb = blockIdx.x;                               // 0..1249
    int b = fb / NFB_B;                                // batch
    int node0 = b * NNODE + (fb - b * NFB_B) * FW;
    int bbase = b * NNODE;
    if (t < FW) dloc[t] = 0u;
    __syncthreads();
#pragma unroll
    for (int r = 0; r < NREP; ++r) {
        int c = (int)min(cursor4[fb * NREP + r], (unsigned)RCAP);
        const unsigned* pb = pairs + (size_t)fb * CAPF + r * RCAP;
        for (int j = t; j < c; j += 256) {
            unsigned p = __builtin_nontemporal_load(pb + j);
            unsigned tl = p >> 16;                     // node local to bucket (0..63)
            unsigned pos = atomicAdd(&dloc[tl], 1u);
            if (pos < SLOT)
                loc[tl * SLOT + pos] = (unsigned short)(p & 0xFFFFu);
        }
    }
    __syncthreads();

    int lane = t & 63;
    int hs = lane & 3;                          // staging head
    int es = lane >> 2;                         // staging edge slot 0..15 per group
    int h32 = lane >> 5;                        // which edge of the pair
    int q = lane & 31;                          // f-quad index 0..31
    int haq = q >> 3;                           // accumulation head for quad
    int nlbase = (t >> 6) * 16;                 // wave's node range
    for (int it = 0; it < 16; ++it) {
        int nl = nlbase + it;
        int node = node0 + nl;
        int dg = min((int)dloc[nl], SLOT);      // wave-uniform
        const unsigned short* sl = loc + nl * SLOT;
        float sH = S[node * NH + hs];

        float v[3];
        int   sb[3];
#pragma unroll
        for (int c = 0; c < 3; ++c) {
            int e = 16 * c + es;
            int s0 = bbase;
            float vv = NEG_BIG;
            if (e < dg) {
                s0 = bbase + (int)sl[e];
                vv = sH + A[s0 * NH + hs];
                vv = vv > 0.f ? vv : NEG_SLOPE * vv;
            }
            sb[c] = s0;
            v[c]  = vv;
        }
        float m = fmaxf(fmaxf(v[0], v[1]), v[2]);
        m = fmaxf(m, __shfl_xor(m, 4));
        m = fmaxf(m, __shfl_xor(m, 8));
        m = fmaxf(m, __shfl_xor(m, 16));
        m = fmaxf(m, __shfl_xor(m, 32));
        float w[3];
#pragma unroll
        for (int c = 0; c < 3; ++c)
            w[c] = (16 * c + es < dg) ? __expf(v[c] - m) : 0.f;

        float4 acc = make_float4(0.f, 0.f, 0.f, 0.f);
#pragma unroll
        for (int i = 0; i < 24; ++i) {
            if (2 * i < dg) {                   // wave-uniform guard
                int e2 = 2 * i + h32;
                float we  = __shfl(w[i >> 3],  4 * (e2 & 15) + haq);
                int   sbe = __shfl(sb[i >> 3], 4 * (e2 & 15));
                const float4 x = *(const float4*)(X + (size_t)sbe * NHF + 4 * q);
                acc.x += x.x * we;
                acc.y += x.y * we;
                acc.z += x.z * we;
                acc.w += x.w * we;
            }
        }
        acc.x += __shfl_xor(acc.x, 32);
        acc.y += __shfl_xor(acc.y, 32);
        acc.z += __shfl_xor(acc.z, 32);
        acc.w += __shfl_xor(acc.w, 32);
        if (lane < 32) {
            float4* o = (float4*)(OUT + (size_t)node * NHF + 4 * q);
            *o = acc;                           // every node written: no OUT init
        }
    }
}

extern "C" void kernel_launch(void* const* d_in, const int* in_sizes, int n_in,
                              void* d_out, int out_size, void* d_ws, size_t ws_size,
                              hipStream_t stream) {
    const float* X  = (const float*)d_in[0];
    const float* As = (const float*)d_in[1];
    const float* Aa = (const float*)d_in[2];
    const int* tg = (const int*)d_in[4];
    const int* sc = (const int*)d_in[5];
    float* OUT = (float*)d_out;

    // Workspace layout, total 10,260,000 B (well under proven-safe 18,240,000;
    // R1 proved ~24.3MB overflows and corrupts harness state):
    //   S       @ 0         : 1,280,000  (SEGN*NH fp32)
    //   A       @ 1,280,000 : 1,280,000
    //   cursor4 @ 2,560,000 :    20,000  (NFB*NREP u32)
    //   pairs   @ 2,580,000 : 7,680,000  (NFB*CAPF u32)
    char* ws = (char*)d_ws;
    float*    S       = (float*)ws;
    float*    A       = (float*)(ws + 1280000);
    unsigned* cursor4 = (unsigned*)(ws + 2560000);
    unsigned* pairs   = (unsigned*)(ws + 2580000);

    hipMemsetAsync(cursor4, 0, NFB * NREP * sizeof(unsigned), stream);
    prep_k<<<SEGN * NH / 256, 256, 0, stream>>>(X, As, Aa, S, A);   // 1250 blocks
    binD_k<<<NBLKD, 256, 0, stream>>>(tg, sc, cursor4, pairs);      // 625 blocks
    gat_k<<<NFB, 256, 0, stream>>>(X, S, A, cursor4, pairs, OUT);   // 1250 blocks
}